// Round 3
// baseline (61052.368 us; speedup 1.0000x reference)
//
#include <hip/hip_runtime.h>
#include <math.h>

typedef float vf4 __attribute__((ext_vector_type(4)));

// Problem dims (fixed by reference)
constexpr int T  = 512;
constexpr int BB = 64;    // batch
constexpr int II = 256;   // input
constexpr int HH = 512;   // hidden

// d_out layout (floats): out[B,T,H] | s[2,B,H] | h[2,B,H] | c[2,B,H]
constexpr int SOFF = BB * T * HH;          // 16777216
constexpr int HOFF = SOFF + 2 * BB * HH;
constexpr int COFF = HOFF + 2 * BB * HH;

// Workspace layout (float offsets). Total ~15.3 MB.
constexpr int WS_WC0 = 0;          // [512 j][768 k] vf4  (Wx0;Wh0 stacked)  1,572,864 f
constexpr int WS_WC1 = 1572864;    // [512 j][1024 k] vf4 (Wx1;Wh1 stacked)  2,097,152 f
constexpr int WS_BH0 = 3670016;    // [512] vf4   2048 f
constexpr int WS_BH1 = 3672064;    // 2048 f
constexpr int WS_HX0 = 3674112;    // h0 exchange, 2 slots [64 b][512 k]  65,536 f
constexpr int WS_HX1 = 3739648;    // h1 exchange, 2 slots               65,536 f
constexpr int WS_SX0 = 3805184;    // spike bits: 4 slots [64 b][8 w] u64 = 2048 u64 (4096 f)
constexpr int WS_CTR = 3809280;    // 8 group counters, 64B-spaced (128 u32)

// ---------------- cache-bypass primitives (MALL-coherent, NO fences) ----------------
// All cross-block traffic uses sc0 sc1 (bypass L1+L2 -> coherent point). This keeps
// the per-XCD L2 weight cache hot: no buffer_inv / buffer_wbl2 is ever executed.

__device__ __forceinline__ void bypass_st(float* p, float v) {
  asm volatile("global_store_dword %0, %1, off sc0 sc1" :: "v"(p), "v"(v) : "memory");
}
__device__ __forceinline__ void bypass_st64(unsigned long long* p, unsigned long long v) {
  asm volatile("global_store_dwordx2 %0, %1, off sc0 sc1" :: "v"(p), "v"(v) : "memory");
}
__device__ __forceinline__ unsigned bypass_ldu(const unsigned* p) {
  unsigned r;
  asm volatile("global_load_dword %0, %1, off sc0 sc1\n\ts_waitcnt vmcnt(0)"
               : "=v"(r) : "v"(p) : "memory");
  return r;
}
__device__ __forceinline__ unsigned long long bypass_ld64(const unsigned long long* p) {
  unsigned long long r;
  asm volatile("global_load_dwordx2 %0, %1, off sc0 sc1\n\ts_waitcnt vmcnt(0)"
               : "=v"(r) : "v"(p) : "memory");
  return r;
}
// 4 outstanding 16B loads, one waitcnt (batched latency)
__device__ __forceinline__ void bypass_ld4x4(const vf4* p0, const vf4* p1,
                                             const vf4* p2, const vf4* p3,
                                             vf4& r0, vf4& r1, vf4& r2, vf4& r3) {
  asm volatile(
      "global_load_dwordx4 %0, %4, off sc0 sc1\n\t"
      "global_load_dwordx4 %1, %5, off sc0 sc1\n\t"
      "global_load_dwordx4 %2, %6, off sc0 sc1\n\t"
      "global_load_dwordx4 %3, %7, off sc0 sc1\n\t"
      "s_waitcnt vmcnt(0)"
      : "=&v"(r0), "=&v"(r1), "=&v"(r2), "=&v"(r3)
      : "v"(p0), "v"(p1), "v"(p2), "v"(p3)
      : "memory");
}

__device__ __forceinline__ float sigf(float x) { return 1.0f / (1.0f + __expf(-x)); }
__device__ __forceinline__ float tanh_fast(float x) {
  return 1.0f - 2.0f / (1.0f + __expf(2.0f * x));
}

// ---------------- setup kernels ----------------

// Wp[j][k] f4 = gates (i,f,g,o) of column j, act-row k; rows k<Ka from A, else B.
// A,B are [K][4*512] reference layout.
__global__ void pack_wc(const float* __restrict__ A, const float* __restrict__ B,
                        int Ka, int K, float* __restrict__ Wp) {
  const int j = blockIdx.x;
  for (int k = threadIdx.x; k < K; k += 256) {
    const float* src = (k < Ka) ? (A + (size_t)k * 2048) : (B + (size_t)(k - Ka) * 2048);
    vf4 v = {src[j], src[512 + j], src[1024 + j], src[1536 + j]};
    ((vf4*)Wp)[(size_t)j * K + k] = v;
  }
}

__global__ void pack_bias(const float* __restrict__ bh0, const float* __restrict__ bh1,
                          float* __restrict__ bh0p, float* __restrict__ bh1p) {
  const int i = blockIdx.x * blockDim.x + threadIdx.x;  // 4096
  if (i < 2048) {
    bh0p[i] = bh0[(i & 3) * 512 + (i >> 2)];
  } else {
    int q = i - 2048;
    bh1p[q] = bh1[(q & 3) * 512 + (q >> 2)];
  }
}

// ---------------- main persistent kernel ----------------
// 512 blocks x 256 threads (2/CU). Block wg = g*64 + s:
//   group g in [0,8): owns batch lanes b in [8g, 8g+8)   (8 independent pipelines)
//   slice s in [0,64): owns h-columns j in [8s, 8s+8)
// wg%8 == s%8 -> all readers of slice s land on one XCD (round-robin heuristic),
// so per-XCD weight working set = 8 slices * 224 KB = 1.75 MB -> L2-resident.
// Thread: o = tid&63 -> (l = o>>3 lane-offset, jo = o&7), kq = tid>>6 k-chunk.
// Per step: dot0 (K=768: [x_t;h0]) -> gates -> spike -> publish(bypass) ->
// 64-way group barrier (MALL counter) -> stage cat1 -> dot1 (K=1024: [s0;h1])
// -> gates -> h1 publish + out write -> stage cat0 for t+1.
__global__ __launch_bounds__(256, 2) void aslstm_main(
    const vf4* __restrict__ Wc0p, const vf4* __restrict__ Wc1p,
    const vf4* __restrict__ bh0p, const vf4* __restrict__ bh1p,
    const float* __restrict__ x,
    float* __restrict__ hx0, float* __restrict__ hx1,
    unsigned long long* __restrict__ sx0b,
    unsigned* __restrict__ ctr,
    float* __restrict__ out) {
  const int wg  = blockIdx.x;
  const int g   = wg >> 6;
  const int s   = wg & 63;
  const int tid = threadIdx.x;
  const int o   = tid & 63;
  const int kq  = tid >> 6;
  const int l   = o >> 3;
  const int jo  = o & 7;
  const int j   = s * 8 + jo;
  const int b   = g * 8 + l;

  __shared__ float cat0[8 * 776];   // [l][x(256) | h0(512)] pad->776 (bank spread)
  __shared__ float cat1[8 * 1032];  // [l][s0(512) | h1(512)] pad->1032
  __shared__ vf4  part[4][64];      // k-chunk partials

  unsigned* ctrp = ctr + g * 16;    // 64B-spaced per-group counter

  float c0 = 0.0f, c1 = 0.0f, sp = 0.0f;

  const vf4* xf4 = (const vf4*)x;

  // ---- stage cat0 for t=0: x[.,0,:] + h0[-1]=0 (hx0 slot 1 is memset) ----
  {
    for (int c = 0; c < 2; ++c) {           // x part: 2 f4/thread
      int fi = tid * 2 + c;                 // [0,512)
      int ll = fi >> 6, k4 = fi & 63;
      vf4 v = xf4[(size_t)(g * 8 + ll) * 32768 + 0 * 64 + k4];
      *(vf4*)&cat0[ll * 776 + 4 * k4] = v;
    }
    int fi = tid * 4;                       // h0 part: 4 f4/thread
    int ll = fi >> 7, kk = fi & 127;
    const vf4* hp = (const vf4*)hx0 + 1 * 8192 + (size_t)(g * 8 + ll) * 128 + kk;
    vf4 r0, r1, r2, r3;
    bypass_ld4x4(hp, hp + 1, hp + 2, hp + 3, r0, r1, r2, r3);
    vf4* d = (vf4*)&cat0[ll * 776 + 256 + 4 * kk];
    d[0] = r0; d[1] = r1; d[2] = r2; d[3] = r3;
  }
  __syncthreads();

  for (int t = 0; t < T; ++t) {
    // ---------- layer 0 dot: [x_t ; h0[t-1]] @ Wc0 ----------
    {
      const vf4* wrow = Wc0p + (size_t)j * 768 + kq * 192;
      const vf4* arow = (const vf4*)(cat0 + l * 776 + kq * 192);
      vf4 acc = {0, 0, 0, 0};
#pragma unroll 4
      for (int k4 = 0; k4 < 48; ++k4) {
        vf4 v = arow[k4];
        vf4 w0 = wrow[4 * k4], w1 = wrow[4 * k4 + 1];
        vf4 w2 = wrow[4 * k4 + 2], w3 = wrow[4 * k4 + 3];
        acc += v.x * w0; acc += v.y * w1; acc += v.z * w2; acc += v.w * w3;
      }
      part[kq][o] = acc;
    }
    __syncthreads();

    // ---------- finalize layer 0 + publish + group barrier (wave 0) ----------
    if (tid < 64) {
      vf4 p = part[0][o] + part[1][o] + part[2][o] + part[3][o] + bh0p[j];
      float cn  = sigf(p.y) * c0 + sigf(p.x) * tanh_fast(p.z);
      float mem = sigf(p.w) * tanh_fast(cn);   // s*0.2*(1-s)==0 for s in {0,1}
      float sn  = (mem > 0.5f) ? 1.0f : 0.0f;
      c0 = cn; sp = sn;
      bypass_st(&hx0[(t & 1) * 32768 + b * 512 + j], mem);
      if (sn != 0.0f) {
        (void)__hip_atomic_fetch_or(&sx0b[(t & 3) * 512 + b * 8 + (j >> 6)],
                                    1ull << (j & 63),
                                    __ATOMIC_RELAXED, __HIP_MEMORY_SCOPE_AGENT);
      }
      if (t == T - 1) {
        out[SOFF + b * 512 + j] = sn;
        out[HOFF + b * 512 + j] = mem;
        out[COFF + b * 512 + j] = cn;
      }
      __builtin_amdgcn_s_waitcnt(0);  // drain bypass stores + atomics (wave 0)
      if (tid == 0) {
        (void)__hip_atomic_fetch_add(ctrp, 1u, __ATOMIC_RELAXED, __HIP_MEMORY_SCOPE_AGENT);
        const unsigned tgt = 64u * (unsigned)(t + 1);
        while (bypass_ldu(ctrp) < tgt) __builtin_amdgcn_s_sleep(2);
      }
    }
    __syncthreads();  // whole block past the group barrier

    // zero duty: spike-bit slot (t+2)&3 (consumers of that slot finished by bar(t-1))
    if ((s & 7) == 0 && tid < 8) {
      bypass_st64(&sx0b[((t + 2) & 3) * 512 + (g * 8 + tid) * 8 + (s >> 3)], 0ull);
    }

    // ---------- stage cat1: s0[t] bits -> floats, h1[t-1] ----------
    {
      int bit = tid * 16;                       // [0, 4096)
      int ll = bit >> 9, pos = bit & 511;
      unsigned long long w =
          bypass_ld64(&sx0b[(t & 3) * 512 + (g * 8 + ll) * 8 + (pos >> 6)]);
      unsigned bits = (unsigned)((w >> (pos & 63)) & 0xFFFFull);
#pragma unroll
      for (int i = 0; i < 16; ++i)
        cat1[ll * 1032 + pos + i] = (bits >> i) & 1 ? 1.0f : 0.0f;

      int fi = tid * 4;                         // h1: 4 f4/thread
      int l2 = fi >> 7, kk = fi & 127;
      const vf4* hp = (const vf4*)hx1 + ((t + 1) & 1) * 8192 + (size_t)(g * 8 + l2) * 128 + kk;
      vf4 r0, r1, r2, r3;
      bypass_ld4x4(hp, hp + 1, hp + 2, hp + 3, r0, r1, r2, r3);
      vf4* d = (vf4*)&cat1[l2 * 1032 + 512 + 4 * kk];
      d[0] = r0; d[1] = r1; d[2] = r2; d[3] = r3;
    }
    __syncthreads();

    // ---------- layer 1 dot: [s0[t] ; h1[t-1]] @ Wc1 ----------
    {
      const vf4* wrow = Wc1p + (size_t)j * 1024 + kq * 256;
      const vf4* arow = (const vf4*)(cat1 + l * 1032 + kq * 256);
      vf4 acc = {0, 0, 0, 0};
#pragma unroll 4
      for (int k4 = 0; k4 < 64; ++k4) {
        vf4 v = arow[k4];
        vf4 w0 = wrow[4 * k4], w1 = wrow[4 * k4 + 1];
        vf4 w2 = wrow[4 * k4 + 2], w3 = wrow[4 * k4 + 3];
        acc += v.x * w0; acc += v.y * w1; acc += v.z * w2; acc += v.w * w3;
      }
      part[kq][o] = acc;
    }
    __syncthreads();

    // ---------- finalize layer 1 ----------
    if (tid < 64) {
      vf4 p = part[0][o] + part[1][o] + part[2][o] + part[3][o] + bh1p[j];
      float cn  = sigf(p.y) * c1 + sigf(p.x) * tanh_fast(p.z);
      float hn  = sigf(p.w) * tanh_fast(cn);
      float h1n = hn * 0.2f + sp;               // output neuron: h*decay + input(spike)
      c1 = cn;
      bypass_st(&hx1[(t & 1) * 32768 + b * 512 + j], h1n);
      out[(size_t)b * (T * 512) + t * 512 + j] = h1n;  // normal cached store
      if (t == T - 1) {
        out[HOFF + 32768 + b * 512 + j] = h1n;
        out[COFF + 32768 + b * 512 + j] = cn;
      }
      // h1n bypass-store is drained by next step's pre-barrier s_waitcnt(0) (same wave)
    }

    // ---------- stage cat0 for t+1 (x[t+1], h0[t]) ----------
    if (t < T - 1) {
      for (int c = 0; c < 2; ++c) {
        int fi = tid * 2 + c;
        int ll = fi >> 6, k4 = fi & 63;
        vf4 v = xf4[(size_t)(g * 8 + ll) * 32768 + (t + 1) * 64 + k4];
        *(vf4*)&cat0[ll * 776 + 4 * k4] = v;
      }
      int fi = tid * 4;
      int ll = fi >> 7, kk = fi & 127;
      const vf4* hp = (const vf4*)hx0 + (t & 1) * 8192 + (size_t)(g * 8 + ll) * 128 + kk;
      vf4 r0, r1, r2, r3;
      bypass_ld4x4(hp, hp + 1, hp + 2, hp + 3, r0, r1, r2, r3);
      vf4* d = (vf4*)&cat0[ll * 776 + 256 + 4 * kk];
      d[0] = r0; d[1] = r1; d[2] = r2; d[3] = r3;
    }
    __syncthreads();
  }
}

// ---------------- launch ----------------

extern "C" void kernel_launch(void* const* d_in, const int* in_sizes, int n_in,
                              void* d_out, int out_size, void* d_ws, size_t ws_size,
                              hipStream_t stream) {
  const float* x   = (const float*)d_in[0];
  const float* Wx0 = (const float*)d_in[1];
  const float* Wh0 = (const float*)d_in[2];
  const float* bh0 = (const float*)d_in[3];
  const float* Wx1 = (const float*)d_in[4];
  const float* Wh1 = (const float*)d_in[5];
  const float* bh1 = (const float*)d_in[6];
  float* out = (float*)d_out;
  float* ws  = (float*)d_ws;

  float* Wc0p  = ws + WS_WC0;
  float* Wc1p  = ws + WS_WC1;
  float* bh0pf = ws + WS_BH0;
  float* bh1pf = ws + WS_BH1;
  float* hx0   = ws + WS_HX0;
  float* hx1   = ws + WS_HX1;
  unsigned long long* sx0b = (unsigned long long*)(ws + WS_SX0);
  unsigned* ctr = (unsigned*)(ws + WS_CTR);

  // zero: h exchange (both slots), spike-bit ring, barrier counters, s1 output
  hipMemsetAsync(hx0, 0, 2 * 64 * 512 * sizeof(float), stream);
  hipMemsetAsync(hx1, 0, 2 * 64 * 512 * sizeof(float), stream);
  hipMemsetAsync(sx0b, 0, 2048 * sizeof(unsigned long long), stream);
  hipMemsetAsync(ctr, 0, 128 * sizeof(unsigned), stream);
  hipMemsetAsync(out + SOFF + BB * HH, 0, BB * HH * sizeof(float), stream);

  pack_wc<<<dim3(512), dim3(256), 0, stream>>>(Wx0, Wh0, 256, 768, Wc0p);
  pack_wc<<<dim3(512), dim3(256), 0, stream>>>(Wx1, Wh1, 512, 1024, Wc1p);
  pack_bias<<<dim3(16), dim3(256), 0, stream>>>(bh0, bh1, bh0pf, bh1pf);

  aslstm_main<<<dim3(512), dim3(256), 0, stream>>>(
      (const vf4*)Wc0p, (const vf4*)Wc1p, (const vf4*)bh0pf, (const vf4*)bh1pf,
      x, hx0, hx1, sx0b, ctr, out);
}

// Round 4
// 14652.837 us; speedup vs baseline: 4.1666x; 4.1666x over previous
//
#include <hip/hip_runtime.h>
#include <math.h>

typedef float vf4 __attribute__((ext_vector_type(4)));

// Problem dims (fixed by reference)
constexpr int T  = 512;
constexpr int BB = 64;    // batch
constexpr int II = 256;   // input
constexpr int HH = 512;   // hidden

// d_out layout (floats): out[B,T,H] | s[2,B,H] | h[2,B,H] | c[2,B,H]
constexpr int SOFF = BB * T * HH;          // 16777216
constexpr int HOFF = SOFF + 2 * BB * HH;
constexpr int COFF = HOFF + 2 * BB * HH;

// Workspace layout (float offsets). ~15.3 MB.
constexpr int WS_WC0 = 0;          // [512 j][768 k] vf4  (Wx0;Wh0 stacked)
constexpr int WS_WC1 = 1572864;    // [512 j][1024 k] vf4 (Wx1;Wh1 stacked)
constexpr int WS_BH0 = 3670016;    // [512] vf4
constexpr int WS_BH1 = 3672064;
constexpr int WS_HX0 = 3674112;    // h0 exchange: [2 slot][8 g][8 b][512 j] f
constexpr int WS_HX1 = 3739648;    // h1 exchange: same
constexpr int WS_SX  = 3805184;    // spike words: [4 slot][8 g][64 w] u64 (4096 f)
constexpr int WS_FLG = 3809280;    // stamps: [8 g][64] u32

// ---------------- MALL-coherent primitives: plain sc0 sc1 ops, ZERO atomics ----
__device__ __forceinline__ void bypass_st(float* p, float v) {
  asm volatile("global_store_dword %0, %1, off sc0 sc1" :: "v"(p), "v"(v) : "memory");
}
__device__ __forceinline__ void bypass_st_u32(unsigned* p, unsigned v) {
  asm volatile("global_store_dword %0, %1, off sc0 sc1" :: "v"(p), "v"(v) : "memory");
}
__device__ __forceinline__ void bypass_st64(unsigned long long* p, unsigned long long v) {
  asm volatile("global_store_dwordx2 %0, %1, off sc0 sc1" :: "v"(p), "v"(v) : "memory");
}
__device__ __forceinline__ unsigned bypass_ldu(const unsigned* p) {
  unsigned r;
  asm volatile("global_load_dword %0, %1, off sc0 sc1\n\ts_waitcnt vmcnt(0)"
               : "=v"(r) : "v"(p) : "memory");
  return r;
}
__device__ __forceinline__ unsigned long long bypass_ld64(const unsigned long long* p) {
  unsigned long long r;
  asm volatile("global_load_dwordx2 %0, %1, off sc0 sc1\n\ts_waitcnt vmcnt(0)"
               : "=v"(r) : "v"(p) : "memory");
  return r;
}
__device__ __forceinline__ void bypass_ld2x4(const vf4* p0, const vf4* p1, vf4& r0, vf4& r1) {
  asm volatile(
      "global_load_dwordx4 %0, %2, off sc0 sc1\n\t"
      "global_load_dwordx4 %1, %3, off sc0 sc1\n\t"
      "s_waitcnt vmcnt(0)"
      : "=&v"(r0), "=&v"(r1) : "v"(p0), "v"(p1) : "memory");
}

__device__ __forceinline__ float sigf(float x) { return 1.0f / (1.0f + __expf(-x)); }
__device__ __forceinline__ float tanh_fast(float x) {
  return 1.0f - 2.0f / (1.0f + __expf(2.0f * x));
}

// ---------------- setup kernels ----------------
// Wp[j][k] f4 = gates (i,f,g,o) of column j, act-row k; rows k<Ka from A, else B.
__global__ void pack_wc(const float* __restrict__ A, const float* __restrict__ B,
                        int Ka, int K, float* __restrict__ Wp) {
  const int j = blockIdx.x;
  for (int k = threadIdx.x; k < K; k += 256) {
    const float* src = (k < Ka) ? (A + (size_t)k * 2048) : (B + (size_t)(k - Ka) * 2048);
    vf4 v = {src[j], src[512 + j], src[1024 + j], src[1536 + j]};
    ((vf4*)Wp)[(size_t)j * K + k] = v;
  }
}

__global__ void pack_bias(const float* __restrict__ bh0, const float* __restrict__ bh1,
                          float* __restrict__ bh0p, float* __restrict__ bh1p) {
  const int i = blockIdx.x * blockDim.x + threadIdx.x;  // 4096
  if (i < 2048) {
    bh0p[i] = bh0[(i & 3) * 512 + (i >> 2)];
  } else {
    int q = i - 2048;
    bh1p[q] = bh1[(q & 3) * 512 + (q >> 2)];
  }
}

// ---------------- main persistent kernel ----------------
// 256 blocks x 512 threads, 1 block/CU (LDS 76.8 KB).
//   g = wg & 7  : batch group, owns batches [8g, 8g+8)  (XCD-robin heuristic)
//   s = wg >> 3 : j-slice in [0,32), owns columns [16s, 16s+16)
// Dot mapping: jo = tid>>5 (16 cols), bp = (tid>>3)&3 (batch pair), kl = tid&7
//   (k-interleave: thread covers k = q*32 + kl*4 .. +3) -> weight loads coalesced,
//   LDS activation reads 2-way max.
// Finalize mapping (tid<128): fjo = tid&15, fb = tid>>4.
// Sync: stamp-store + poll, all sc0 sc1, one barrier per step.
__global__ __launch_bounds__(512, 2) void aslstm_main(
    const vf4* __restrict__ Wc0p, const vf4* __restrict__ Wc1p,
    const vf4* __restrict__ bh0p, const vf4* __restrict__ bh1p,
    const float* __restrict__ x,
    float* __restrict__ hx0, float* __restrict__ hx1,
    unsigned long long* __restrict__ sx,
    unsigned* __restrict__ flags,
    float* __restrict__ out) {
  const int wg  = blockIdx.x;
  const int g   = wg & 7;
  const int s   = wg >> 3;
  const int tid = threadIdx.x;
  const int jo  = tid >> 5;
  const int bp  = (tid >> 3) & 3;
  const int kl  = tid & 7;
  const int j   = s * 16 + jo;
  const int fjo = tid & 15;
  const int fb  = tid >> 4;           // valid when tid<128
  const int fj  = s * 16 + fjo;

  __shared__ float cat0[8][776];      // [b][ x(256) | h0(512) | pad ]
  __shared__ float cat1[8][1032];     // [b][ s0(512) | h1(512) | pad ]
  __shared__ vf4  part[16][8][9];     // [jo][b][kl] (pad 9)
  __shared__ unsigned long long swords[64];

  float c0 = 0.0f, c1 = 0.0f, sp = 0.0f;

  // ---- initial cat0: x[t=0] + h0[-1]=0 (hx0 slot 1 is memset) ----
  {
    int idx = tid * 4;  int b = idx >> 8, k = idx & 255;
    *(vf4*)&cat0[b][k] = *(const vf4*)&x[(size_t)(g * 8 + b) * (T * II) + k];
    int i2 = tid * 8;   int b2 = i2 >> 9, jj = i2 & 511;
    const vf4* hp = (const vf4*)(hx0 + 32768 + g * 4096 + b2 * 512 + jj);
    vf4 r0, r1;  bypass_ld2x4(hp, hp + 1, r0, r1);
    *(vf4*)&cat0[b2][256 + jj] = r0;  *(vf4*)&cat0[b2][256 + jj + 4] = r1;
  }
  __syncthreads();

  for (int t = 0; t < T; ++t) {
    // ---------- dot0: [x_t ; h0[t-1]] @ Wc0 (K=768) ----------
    {
      const vf4* wr = Wc0p + (size_t)j * 768;
      vf4 a0 = {0, 0, 0, 0}, a1 = {0, 0, 0, 0};
      const int b0 = bp * 2, b1 = b0 + 1;
#pragma unroll 4
      for (int q = 0; q < 24; ++q) {
        int k = q * 32 + kl * 4;
        vf4 w0 = wr[k], w1 = wr[k + 1], w2 = wr[k + 2], w3 = wr[k + 3];
        vf4 av0 = *(const vf4*)&cat0[b0][k];
        vf4 av1 = *(const vf4*)&cat0[b1][k];
        a0 += av0.x * w0; a0 += av0.y * w1; a0 += av0.z * w2; a0 += av0.w * w3;
        a1 += av1.x * w0; a1 += av1.y * w1; a1 += av1.z * w2; a1 += av1.w * w3;
      }
      part[jo][b0][kl] = a0;  part[jo][b1][kl] = a1;
    }
    __syncthreads();  // S1

    // ---------- finalize layer 0: gates, spike, publish ----------
    if (tid < 128) {
      vf4 p = part[fjo][fb][0];
#pragma unroll
      for (int kk = 1; kk < 8; ++kk) p += part[fjo][fb][kk];
      p += bh0p[fj];
      float cn  = sigf(p.y) * c0 + sigf(p.x) * tanh_fast(p.z);
      float mem = sigf(p.w) * tanh_fast(cn);   // s*0.2*(1-s) == 0 for s in {0,1}
      float sn  = (mem > 0.5f) ? 1.0f : 0.0f;
      c0 = cn; sp = sn;
      bypass_st(&hx0[(t & 1) * 32768 + g * 4096 + fb * 512 + fj], mem);
      unsigned long long ball = __ballot(sn != 0.0f);   // full wave active
      if ((tid & 63) == 0)
        bypass_st64(&sx[(size_t)(t & 3) * 512 + g * 64 + s * 2 + (tid >> 6)], ball);
      if (t == T - 1) {
        out[SOFF + (g * 8 + fb) * 512 + fj] = sn;
        out[HOFF + (g * 8 + fb) * 512 + fj] = mem;
        out[COFF + (g * 8 + fb) * 512 + fj] = cn;
      }
    }
    __syncthreads();  // S2 — compiler drains all vmcnt before s_barrier

    // ---------- group barrier: stamp store + poll (no atomics) ----------
    if (tid == 0) bypass_st_u32(&flags[g * 64 + s], (unsigned)(t + 1));
    if (tid < 64) {
      const unsigned tgt = (unsigned)(t + 1);
      for (;;) {
        unsigned v = bypass_ldu(&flags[g * 64 + (tid & 31)]);
        if (__all((int)(v >= tgt))) break;
        __builtin_amdgcn_s_sleep(1);
      }
      swords[tid] = bypass_ld64(&sx[(size_t)(t & 3) * 512 + g * 64 + tid]);
    }
    __syncthreads();  // S3

    // ---------- stage cat1: spike bits -> floats, h1[t-1] ----------
    {
      int widx = tid >> 3, q = tid & 7;
      int h = widx & 1, s2 = widx >> 1;
      int bq = h * 4 + (q >> 1);
      int jh = q & 1;
      unsigned bits = (unsigned)(swords[widx] >> ((q >> 1) * 16 + jh * 8)) & 0xFFu;
      vf4 f0, f1;
      f0.x = (float)((bits >> 0) & 1); f0.y = (float)((bits >> 1) & 1);
      f0.z = (float)((bits >> 2) & 1); f0.w = (float)((bits >> 3) & 1);
      f1.x = (float)((bits >> 4) & 1); f1.y = (float)((bits >> 5) & 1);
      f1.z = (float)((bits >> 6) & 1); f1.w = (float)((bits >> 7) & 1);
      *(vf4*)&cat1[bq][s2 * 16 + jh * 8]     = f0;
      *(vf4*)&cat1[bq][s2 * 16 + jh * 8 + 4] = f1;

      int i2 = tid * 8;  int b2 = i2 >> 9, jj = i2 & 511;
      const vf4* hp = (const vf4*)(hx1 + ((t + 1) & 1) * 32768 + g * 4096 + b2 * 512 + jj);
      vf4 r0, r1;  bypass_ld2x4(hp, hp + 1, r0, r1);
      *(vf4*)&cat1[b2][512 + jj] = r0;  *(vf4*)&cat1[b2][512 + jj + 4] = r1;
    }
    __syncthreads();  // S4

    // ---------- dot1: [s0[t] ; h1[t-1]] @ Wc1 (K=1024) ----------
    {
      const vf4* wr = Wc1p + (size_t)j * 1024;
      vf4 a0 = {0, 0, 0, 0}, a1 = {0, 0, 0, 0};
      const int b0 = bp * 2, b1 = b0 + 1;
#pragma unroll 4
      for (int q = 0; q < 32; ++q) {
        int k = q * 32 + kl * 4;
        vf4 w0 = wr[k], w1 = wr[k + 1], w2 = wr[k + 2], w3 = wr[k + 3];
        vf4 av0 = *(const vf4*)&cat1[b0][k];
        vf4 av1 = *(const vf4*)&cat1[b1][k];
        a0 += av0.x * w0; a0 += av0.y * w1; a0 += av0.z * w2; a0 += av0.w * w3;
        a1 += av1.x * w0; a1 += av1.y * w1; a1 += av1.z * w2; a1 += av1.w * w3;
      }
      part[jo][b0][kl] = a0;  part[jo][b1][kl] = a1;
    }
    __syncthreads();  // S5

    // ---------- finalize layer 1 + stage cat0 for t+1 ----------
    if (tid < 128) {
      vf4 p = part[fjo][fb][0];
#pragma unroll
      for (int kk = 1; kk < 8; ++kk) p += part[fjo][fb][kk];
      p += bh1p[fj];
      float cn  = sigf(p.y) * c1 + sigf(p.x) * tanh_fast(p.z);
      float hn  = sigf(p.w) * tanh_fast(cn);
      float h1n = hn * 0.2f + sp;             // output neuron: h*decay + input(spike)
      c1 = cn;
      bypass_st(&hx1[(t & 1) * 32768 + g * 4096 + fb * 512 + fj], h1n);
      out[(size_t)(g * 8 + fb) * (T * 512) + (size_t)t * 512 + fj] = h1n;
      if (t == T - 1) {
        out[HOFF + 32768 + (g * 8 + fb) * 512 + fj] = h1n;
        out[COFF + 32768 + (g * 8 + fb) * 512 + fj] = cn;
      }
    }
    if (t < T - 1) {
      int idx = tid * 4;  int b = idx >> 8, k = idx & 255;
      *(vf4*)&cat0[b][k] =
          *(const vf4*)&x[(size_t)(g * 8 + b) * (T * II) + (size_t)(t + 1) * II + k];
      int i2 = tid * 8;   int b2 = i2 >> 9, jj = i2 & 511;
      const vf4* hp = (const vf4*)(hx0 + (t & 1) * 32768 + g * 4096 + b2 * 512 + jj);
      vf4 r0, r1;  bypass_ld2x4(hp, hp + 1, r0, r1);
      *(vf4*)&cat0[b2][256 + jj] = r0;  *(vf4*)&cat0[b2][256 + jj + 4] = r1;
    }
    __syncthreads();  // S6
  }
}

// ---------------- launch ----------------
extern "C" void kernel_launch(void* const* d_in, const int* in_sizes, int n_in,
                              void* d_out, int out_size, void* d_ws, size_t ws_size,
                              hipStream_t stream) {
  const float* x   = (const float*)d_in[0];
  const float* Wx0 = (const float*)d_in[1];
  const float* Wh0 = (const float*)d_in[2];
  const float* bh0 = (const float*)d_in[3];
  const float* Wx1 = (const float*)d_in[4];
  const float* Wh1 = (const float*)d_in[5];
  const float* bh1 = (const float*)d_in[6];
  float* out = (float*)d_out;
  float* ws  = (float*)d_ws;

  float* Wc0p  = ws + WS_WC0;
  float* Wc1p  = ws + WS_WC1;
  float* bh0pf = ws + WS_BH0;
  float* bh1pf = ws + WS_BH1;
  float* hx0   = ws + WS_HX0;
  float* hx1   = ws + WS_HX1;
  unsigned long long* sx = (unsigned long long*)(ws + WS_SX);
  unsigned* flags = (unsigned*)(ws + WS_FLG);

  // zero: h exchanges (both slots), spike words, stamps, s1 output section
  hipMemsetAsync(hx0, 0, 2 * 64 * 512 * sizeof(float), stream);
  hipMemsetAsync(hx1, 0, 2 * 64 * 512 * sizeof(float), stream);
  hipMemsetAsync(sx, 0, 2048 * sizeof(unsigned long long), stream);
  hipMemsetAsync(flags, 0, 512 * sizeof(unsigned), stream);
  hipMemsetAsync(out + SOFF + BB * HH, 0, BB * HH * sizeof(float), stream);

  pack_wc<<<dim3(512), dim3(256), 0, stream>>>(Wx0, Wh0, 256, 768, Wc0p);
  pack_wc<<<dim3(512), dim3(256), 0, stream>>>(Wx1, Wh1, 512, 1024, Wc1p);
  pack_bias<<<dim3(16), dim3(256), 0, stream>>>(bh0, bh1, bh0pf, bh1pf);

  aslstm_main<<<dim3(256), dim3(512), 0, stream>>>(
      (const vf4*)Wc0p, (const vf4*)Wc1p, (const vf4*)bh0pf, (const vf4*)bh1pf,
      x, hx0, hx1, sx, flags, out);
}

// Round 5
// 14388.591 us; speedup vs baseline: 4.2431x; 1.0184x over previous
//
#include <hip/hip_runtime.h>
#include <math.h>

typedef float vf4 __attribute__((ext_vector_type(4)));

// Problem dims (fixed by reference)
constexpr int T  = 512;
constexpr int BB = 64;    // batch
constexpr int II = 256;   // input
constexpr int HH = 512;   // hidden

// d_out layout (floats): out[B,T,H] | s[2,B,H] | h[2,B,H] | c[2,B,H]
constexpr int SOFF = BB * T * HH;          // 16777216
constexpr int HOFF = SOFF + 2 * BB * HH;
constexpr int COFF = HOFF + 2 * BB * HH;

// Workspace layout (float offsets). ~15.3 MB.
constexpr int WS_WC0 = 0;          // [512 j][768 k] vf4  (Wx0;Wh0 stacked)
constexpr int WS_WC1 = 1572864;    // [512 j][1024 k] vf4 (Wx1;Wh1 stacked)
constexpr int WS_BH0 = 3670016;    // [512] vf4
constexpr int WS_BH1 = 3672064;
constexpr int WS_HX0 = 3674112;    // h0 exchange: [2 slot][8 g][8 b][512 j] f
constexpr int WS_HX1 = 3739648;    // h1 exchange: same
constexpr int WS_SX  = 3805184;    // spike words: [4 slot][8 g][64 w] u64 (4096 f)
constexpr int WS_FLG = 3809280;    // stamps: [8 g][64] u32

// ---------------- MALL-coherent primitives: plain sc0 sc1 ops, ZERO atomics ----
__device__ __forceinline__ void bypass_st(float* p, float v) {
  asm volatile("global_store_dword %0, %1, off sc0 sc1" :: "v"(p), "v"(v) : "memory");
}
__device__ __forceinline__ void bypass_st_u32(unsigned* p, unsigned v) {
  asm volatile("global_store_dword %0, %1, off sc0 sc1" :: "v"(p), "v"(v) : "memory");
}
__device__ __forceinline__ void bypass_st64(unsigned long long* p, unsigned long long v) {
  asm volatile("global_store_dwordx2 %0, %1, off sc0 sc1" :: "v"(p), "v"(v) : "memory");
}
__device__ __forceinline__ unsigned bypass_ldu(const unsigned* p) {
  unsigned r;
  asm volatile("global_load_dword %0, %1, off sc0 sc1\n\ts_waitcnt vmcnt(0)"
               : "=v"(r) : "v"(p) : "memory");
  return r;
}
__device__ __forceinline__ unsigned long long bypass_ld64(const unsigned long long* p) {
  unsigned long long r;
  asm volatile("global_load_dwordx2 %0, %1, off sc0 sc1\n\ts_waitcnt vmcnt(0)"
               : "=v"(r) : "v"(p) : "memory");
  return r;
}
__device__ __forceinline__ void bypass_ld2x4(const vf4* p0, const vf4* p1, vf4& r0, vf4& r1) {
  asm volatile(
      "global_load_dwordx4 %0, %2, off sc0 sc1\n\t"
      "global_load_dwordx4 %1, %3, off sc0 sc1\n\t"
      "s_waitcnt vmcnt(0)"
      : "=&v"(r0), "=&v"(r1) : "v"(p0), "v"(p1) : "memory");
}

__device__ __forceinline__ float sigf(float x) { return 1.0f / (1.0f + __expf(-x)); }
__device__ __forceinline__ float tanh_fast(float x) {
  return 1.0f - 2.0f / (1.0f + __expf(2.0f * x));
}

// ---------------- setup kernels ----------------
// Wp[j][k] f4 = gates (i,f,g,o) of column j, act-row k; rows k<Ka from A, else B.
__global__ void pack_wc(const float* __restrict__ A, const float* __restrict__ B,
                        int Ka, int K, float* __restrict__ Wp) {
  const int j = blockIdx.x;
  for (int k = threadIdx.x; k < K; k += 256) {
    const float* src = (k < Ka) ? (A + (size_t)k * 2048) : (B + (size_t)(k - Ka) * 2048);
    vf4 v = {src[j], src[512 + j], src[1024 + j], src[1536 + j]};
    ((vf4*)Wp)[(size_t)j * K + k] = v;
  }
}

__global__ void pack_bias(const float* __restrict__ bh0, const float* __restrict__ bh1,
                          float* __restrict__ bh0p, float* __restrict__ bh1p) {
  const int i = blockIdx.x * blockDim.x + threadIdx.x;  // 4096
  if (i < 2048) {
    bh0p[i] = bh0[(i & 3) * 512 + (i >> 2)];
  } else {
    int q = i - 2048;
    bh1p[q] = bh1[(q & 3) * 512 + (q >> 2)];
  }
}

// ---------------- main persistent kernel ----------------
// 256 blocks x 512 threads, 1 block/CU (LDS 76.8 KB).
// XCD-locality remap (round 5): dispatch is assumed round-robin wg%8 -> XCD.
//   xcd = wg & 7; r = wg >> 3; g = r & 7 (batch group); s = (r>>3)*8 + xcd.
// => XCD x hosts slices {x, 8+x, 16+x, 24+x} for ALL 8 groups: unique weight
//    working set per XCD = 64 j-cols * 28.7 KB = 1.84 MB -> L2-resident.
//    (Round 4 had g = wg&7: each XCD streamed the full 14.7 MB every step ->
//     59 MB/step past L2 = the whole 29 us step time.)
// Dot mapping: jo = tid>>5 (16 cols), bp = (tid>>3)&3 (batch pair), kl = tid&7.
// Finalize mapping (tid<128): fjo = tid&15, fb = tid>>4.
// Sync: stamp-store + poll, all sc0 sc1, one 64-wide group barrier per step.
__global__ __launch_bounds__(512, 2) void aslstm_main(
    const vf4* __restrict__ Wc0p, const vf4* __restrict__ Wc1p,
    const vf4* __restrict__ bh0p, const vf4* __restrict__ bh1p,
    const float* __restrict__ x,
    float* __restrict__ hx0, float* __restrict__ hx1,
    unsigned long long* __restrict__ sx,
    unsigned* __restrict__ flags,
    float* __restrict__ out) {
  const int wg  = blockIdx.x;
  const int xcd = wg & 7;
  const int r   = wg >> 3;
  const int g   = r & 7;
  const int s   = (r >> 3) * 8 + xcd;
  const int tid = threadIdx.x;
  const int jo  = tid >> 5;
  const int bp  = (tid >> 3) & 3;
  const int kl  = tid & 7;
  const int j   = s * 16 + jo;
  const int fjo = tid & 15;
  const int fb  = tid >> 4;           // valid when tid<128
  const int fj  = s * 16 + fjo;

  __shared__ float cat0[8][776];      // [b][ x(256) | h0(512) | pad ]
  __shared__ float cat1[8][1032];     // [b][ s0(512) | h1(512) | pad ]
  __shared__ vf4  part[16][8][9];     // [jo][b][kl] (pad 9)
  __shared__ unsigned long long swords[64];

  float c0 = 0.0f, c1 = 0.0f, sp = 0.0f;

  // ---- initial cat0: x[t=0] + h0[-1]=0 (hx0 slot 1 is memset) ----
  {
    int idx = tid * 4;  int b = idx >> 8, k = idx & 255;
    *(vf4*)&cat0[b][k] = *(const vf4*)&x[(size_t)(g * 8 + b) * (T * II) + k];
    int i2 = tid * 8;   int b2 = i2 >> 9, jj = i2 & 511;
    const vf4* hp = (const vf4*)(hx0 + 32768 + g * 4096 + b2 * 512 + jj);
    vf4 r0, r1;  bypass_ld2x4(hp, hp + 1, r0, r1);
    *(vf4*)&cat0[b2][256 + jj] = r0;  *(vf4*)&cat0[b2][256 + jj + 4] = r1;
  }
  __syncthreads();

  for (int t = 0; t < T; ++t) {
    // ---------- dot0: [x_t ; h0[t-1]] @ Wc0 (K=768) ----------
    {
      const vf4* wr = Wc0p + (size_t)j * 768;
      vf4 a0 = {0, 0, 0, 0}, a1 = {0, 0, 0, 0};
      const int b0 = bp * 2, b1 = b0 + 1;
#pragma unroll 4
      for (int q = 0; q < 24; ++q) {
        int k = q * 32 + kl * 4;
        vf4 w0 = wr[k], w1 = wr[k + 1], w2 = wr[k + 2], w3 = wr[k + 3];
        vf4 av0 = *(const vf4*)&cat0[b0][k];
        vf4 av1 = *(const vf4*)&cat0[b1][k];
        a0 += av0.x * w0; a0 += av0.y * w1; a0 += av0.z * w2; a0 += av0.w * w3;
        a1 += av1.x * w0; a1 += av1.y * w1; a1 += av1.z * w2; a1 += av1.w * w3;
      }
      part[jo][b0][kl] = a0;  part[jo][b1][kl] = a1;
    }
    __syncthreads();  // S1

    // ---------- finalize layer 0: gates, spike, publish ----------
    if (tid < 128) {
      vf4 p = part[fjo][fb][0];
#pragma unroll
      for (int kk = 1; kk < 8; ++kk) p += part[fjo][fb][kk];
      p += bh0p[fj];
      float cn  = sigf(p.y) * c0 + sigf(p.x) * tanh_fast(p.z);
      float mem = sigf(p.w) * tanh_fast(cn);   // s*0.2*(1-s) == 0 for s in {0,1}
      float sn  = (mem > 0.5f) ? 1.0f : 0.0f;
      c0 = cn; sp = sn;
      bypass_st(&hx0[(t & 1) * 32768 + g * 4096 + fb * 512 + fj], mem);
      unsigned long long ball = __ballot(sn != 0.0f);   // full wave active
      if ((tid & 63) == 0)
        bypass_st64(&sx[(size_t)(t & 3) * 512 + g * 64 + s * 2 + (tid >> 6)], ball);
      if (t == T - 1) {
        out[SOFF + (g * 8 + fb) * 512 + fj] = sn;
        out[HOFF + (g * 8 + fb) * 512 + fj] = mem;
        out[COFF + (g * 8 + fb) * 512 + fj] = cn;
      }
    }
    __syncthreads();  // S2 — compiler drains all vmcnt before s_barrier

    // ---------- group barrier: stamp store + poll (no atomics) ----------
    if (tid == 0) bypass_st_u32(&flags[g * 64 + s], (unsigned)(t + 1));
    if (tid < 64) {
      const unsigned tgt = (unsigned)(t + 1);
      for (;;) {
        unsigned v = bypass_ldu(&flags[g * 64 + (tid & 31)]);
        if (__all((int)(v >= tgt))) break;
        __builtin_amdgcn_s_sleep(1);
      }
      swords[tid] = bypass_ld64(&sx[(size_t)(t & 3) * 512 + g * 64 + tid]);
    }
    __syncthreads();  // S3

    // ---------- stage cat1: spike bits -> floats, h1[t-1] ----------
    {
      int widx = tid >> 3, q = tid & 7;
      int h = widx & 1, s2 = widx >> 1;
      int bq = h * 4 + (q >> 1);
      int jh = q & 1;
      unsigned bits = (unsigned)(swords[widx] >> ((q >> 1) * 16 + jh * 8)) & 0xFFu;
      vf4 f0, f1;
      f0.x = (float)((bits >> 0) & 1); f0.y = (float)((bits >> 1) & 1);
      f0.z = (float)((bits >> 2) & 1); f0.w = (float)((bits >> 3) & 1);
      f1.x = (float)((bits >> 4) & 1); f1.y = (float)((bits >> 5) & 1);
      f1.z = (float)((bits >> 6) & 1); f1.w = (float)((bits >> 7) & 1);
      *(vf4*)&cat1[bq][s2 * 16 + jh * 8]     = f0;
      *(vf4*)&cat1[bq][s2 * 16 + jh * 8 + 4] = f1;

      int i2 = tid * 8;  int b2 = i2 >> 9, jj = i2 & 511;
      const vf4* hp = (const vf4*)(hx1 + ((t + 1) & 1) * 32768 + g * 4096 + b2 * 512 + jj);
      vf4 r0, r1;  bypass_ld2x4(hp, hp + 1, r0, r1);
      *(vf4*)&cat1[b2][512 + jj] = r0;  *(vf4*)&cat1[b2][512 + jj + 4] = r1;
    }
    __syncthreads();  // S4

    // ---------- dot1: [s0[t] ; h1[t-1]] @ Wc1 (K=1024) ----------
    {
      const vf4* wr = Wc1p + (size_t)j * 1024;
      vf4 a0 = {0, 0, 0, 0}, a1 = {0, 0, 0, 0};
      const int b0 = bp * 2, b1 = b0 + 1;
#pragma unroll 4
      for (int q = 0; q < 32; ++q) {
        int k = q * 32 + kl * 4;
        vf4 w0 = wr[k], w1 = wr[k + 1], w2 = wr[k + 2], w3 = wr[k + 3];
        vf4 av0 = *(const vf4*)&cat1[b0][k];
        vf4 av1 = *(const vf4*)&cat1[b1][k];
        a0 += av0.x * w0; a0 += av0.y * w1; a0 += av0.z * w2; a0 += av0.w * w3;
        a1 += av1.x * w0; a1 += av1.y * w1; a1 += av1.z * w2; a1 += av1.w * w3;
      }
      part[jo][b0][kl] = a0;  part[jo][b1][kl] = a1;
    }
    __syncthreads();  // S5

    // ---------- finalize layer 1 + stage cat0 for t+1 ----------
    if (tid < 128) {
      vf4 p = part[fjo][fb][0];
#pragma unroll
      for (int kk = 1; kk < 8; ++kk) p += part[fjo][fb][kk];
      p += bh1p[fj];
      float cn  = sigf(p.y) * c1 + sigf(p.x) * tanh_fast(p.z);
      float hn  = sigf(p.w) * tanh_fast(cn);
      float h1n = hn * 0.2f + sp;             // output neuron: h*decay + input(spike)
      c1 = cn;
      bypass_st(&hx1[(t & 1) * 32768 + g * 4096 + fb * 512 + fj], h1n);
      out[(size_t)(g * 8 + fb) * (T * 512) + (size_t)t * 512 + fj] = h1n;
      if (t == T - 1) {
        out[HOFF + 32768 + (g * 8 + fb) * 512 + fj] = h1n;
        out[COFF + 32768 + (g * 8 + fb) * 512 + fj] = cn;
      }
    }
    if (t < T - 1) {
      int idx = tid * 4;  int b = idx >> 8, k = idx & 255;
      *(vf4*)&cat0[b][k] =
          *(const vf4*)&x[(size_t)(g * 8 + b) * (T * II) + (size_t)(t + 1) * II + k];
      int i2 = tid * 8;   int b2 = i2 >> 9, jj = i2 & 511;
      const vf4* hp = (const vf4*)(hx0 + (t & 1) * 32768 + g * 4096 + b2 * 512 + jj);
      vf4 r0, r1;  bypass_ld2x4(hp, hp + 1, r0, r1);
      *(vf4*)&cat0[b2][256 + jj] = r0;  *(vf4*)&cat0[b2][256 + jj + 4] = r1;
    }
    __syncthreads();  // S6
  }
}

// ---------------- launch ----------------
extern "C" void kernel_launch(void* const* d_in, const int* in_sizes, int n_in,
                              void* d_out, int out_size, void* d_ws, size_t ws_size,
                              hipStream_t stream) {
  const float* x   = (const float*)d_in[0];
  const float* Wx0 = (const float*)d_in[1];
  const float* Wh0 = (const float*)d_in[2];
  const float* bh0 = (const float*)d_in[3];
  const float* Wx1 = (const float*)d_in[4];
  const float* Wh1 = (const float*)d_in[5];
  const float* bh1 = (const float*)d_in[6];
  float* out = (float*)d_out;
  float* ws  = (float*)d_ws;

  float* Wc0p  = ws + WS_WC0;
  float* Wc1p  = ws + WS_WC1;
  float* bh0pf = ws + WS_BH0;
  float* bh1pf = ws + WS_BH1;
  float* hx0   = ws + WS_HX0;
  float* hx1   = ws + WS_HX1;
  unsigned long long* sx = (unsigned long long*)(ws + WS_SX);
  unsigned* flags = (unsigned*)(ws + WS_FLG);

  // zero: h exchanges (both slots), spike words, stamps, s1 output section
  hipMemsetAsync(hx0, 0, 2 * 64 * 512 * sizeof(float), stream);
  hipMemsetAsync(hx1, 0, 2 * 64 * 512 * sizeof(float), stream);
  hipMemsetAsync(sx, 0, 2048 * sizeof(unsigned long long), stream);
  hipMemsetAsync(flags, 0, 512 * sizeof(unsigned), stream);
  hipMemsetAsync(out + SOFF + BB * HH, 0, BB * HH * sizeof(float), stream);

  pack_wc<<<dim3(512), dim3(256), 0, stream>>>(Wx0, Wh0, 256, 768, Wc0p);
  pack_wc<<<dim3(512), dim3(256), 0, stream>>>(Wx1, Wh1, 512, 1024, Wc1p);
  pack_bias<<<dim3(16), dim3(256), 0, stream>>>(bh0, bh1, bh0pf, bh1pf);

  aslstm_main<<<dim3(256), dim3(512), 0, stream>>>(
      (const vf4*)Wc0p, (const vf4*)Wc1p, (const vf4*)bh0pf, (const vf4*)bh1pf,
      x, hx0, hx1, sx, flags, out);
}